// Round 16
// baseline (173.300 us; speedup 1.0000x reference)
//
#include <hip/hip_runtime.h>

#define BB 8
#define CC 256
#define DD 128
#define NN 4096
#define BN_EPS 1e-5f
#define NSPLIT 5

typedef _Float16 f16;
typedef _Float16 half8 __attribute__((ext_vector_type(8)));
typedef _Float16 half2t __attribute__((ext_vector_type(2)));
typedef float f32x4 __attribute__((ext_vector_type(4)));

__device__ __forceinline__ f32x4 mfma16(half8 a, half8 b, f32x4 c) {
  return __builtin_amdgcn_mfma_f32_16x16x32_f16(a, b, c, 0, 0, 0);
}

__device__ __forceinline__ void gload_lds16(const void* g, void* l) {
  __builtin_amdgcn_global_load_lds((const __attribute__((address_space(1))) void*)g,
                                   (__attribute__((address_space(3))) void*)l, 16, 0, 0);
}

__device__ __forceinline__ half2t pkrtz(float a, float b) {
  auto t = __builtin_amdgcn_cvt_pkrtz(a, b);
  return __builtin_bit_cast(half2t, t);
}

#define EXP2(x) __builtin_amdgcn_exp2f(x)

// key permutation for 32-key tiles: swapped-QK register layout feeds PV A-frag directly.
#define PERM32(i) ((((i) >> 2) & 3) * 8 + (((i) >> 4) & 1) * 4 + ((i) & 3))

// ---------- weights cast (fp32 -> fp16), stats zero ----------
__global__ void k_cast_weights(const float* __restrict__ tw, const float* __restrict__ pw,
                               const float* __restrict__ gw, const float* __restrict__ ww,
                               f16* __restrict__ Wcat, f16* __restrict__ Wwh,
                               float* __restrict__ stats) {
  int i = blockIdx.x * 256 + threadIdx.x;
  if (i < 32768) Wcat[i] = (f16)tw[i];
  else if (i < 65536) Wcat[i] = (f16)pw[i - 32768];
  else if (i < 98304) Wcat[i] = (f16)gw[i - 65536];
  else if (i < 131072) Wwh[i - 98304] = (f16)ww[i - 98304];
  if (i < 512) stats[i] = 0.f;
}

// ---------- fused projections: x staged+transposed in LDS, G transposed in LDS ----------
__global__ __launch_bounds__(256) void k_gemm1(const float* __restrict__ x, const f16* __restrict__ Wcat,
                                               f16* __restrict__ T, f16* __restrict__ P,
                                               f16* __restrict__ Gdn) {
  __shared__ char xls[32768];  // xl[n 64][c 256] f16, granule-swizzled
  __shared__ char gls[16384];  // gl[n 64][d 128] f16, granule-swizzled
  int b = blockIdx.y;
  int n0 = blockIdx.x * 64;
  int tid = threadIdx.x;
  int lane = tid & 63, wave = tid >> 6;
  int lr = lane & 15, lg = lane >> 4;
  int wr = wave >> 1, wc = wave & 1;

  {
    int c = tid;
    const float* src = x + ((size_t)b * CC + c) * NN + n0;
#pragma unroll
    for (int n4 = 0; n4 < 64; n4 += 4) {
      f32x4 v = *(const f32x4*)(src + n4);
#pragma unroll
      for (int k = 0; k < 4; ++k) {
        int n = n4 + k;
        *(f16*)(xls + n * 512 + ((((c >> 3) ^ (n & 7)) * 8 + (c & 7)) * 2)) = (f16)v[k];
      }
    }
  }
  __syncthreads();

  half8 a[2][8];
#pragma unroll
  for (int i = 0; i < 2; ++i) {
    int nloc = wr * 32 + i * 16 + lr;
#pragma unroll
    for (int k0 = 0; k0 < 8; ++k0)
      a[i][k0] = *(const half8*)(xls + nloc * 512 + (((k0 * 4 + lg) ^ (nloc & 7)) << 4));
  }

  size_t base = (size_t)b * NN + n0;
#pragma unroll
  for (int yb = 0; yb < 6; ++yb) {
    int c0 = yb * 64 + wc * 32;
    f32x4 acc[2][2] = {};
#pragma unroll
    for (int k0 = 0; k0 < 8; ++k0) {
      half8 w[2];
      for (int j = 0; j < 2; ++j)
        w[j] = *(const half8*)(Wcat + (size_t)(c0 + j * 16 + lr) * CC + k0 * 32 + lg * 8);
      for (int i = 0; i < 2; ++i)
        for (int j = 0; j < 2; ++j)
          acc[i][j] = mfma16(a[i][k0], w[j], acc[i][j]);
    }
    if (yb < 4) {
      f16* dst = (yb < 2) ? T : P;
      int cl0 = (yb & 1) * 64 + wc * 32;
      for (int i = 0; i < 2; ++i)
        for (int j = 0; j < 2; ++j)
          for (int r = 0; r < 4; ++r) {
            int row = wr * 32 + i * 16 + lg * 4 + r;
            int col = cl0 + j * 16 + lr;
            dst[(base + row) * DD + col] = (f16)acc[i][j][r];
          }
    } else {
      for (int i = 0; i < 2; ++i)
        for (int j = 0; j < 2; ++j)
          for (int r = 0; r < 4; ++r) {
            int n = wr * 32 + i * 16 + lg * 4 + r;
            int d = (yb - 4) * 64 + wc * 32 + j * 16 + lr;
            *(f16*)(gls + n * 256 + ((((d >> 3) ^ (n & 7)) * 8 + (d & 7)) * 2)) = (f16)acc[i][j][r];
          }
    }
  }
  __syncthreads();
  {
    int d = tid >> 1, nh = (tid & 1) * 32;
    f16 tmp[32];
#pragma unroll
    for (int k = 0; k < 32; ++k) {
      int n = nh + k;
      tmp[k] = *(const f16*)(gls + n * 256 + ((((d >> 3) ^ (n & 7)) * 8 + (d & 7)) * 2));
    }
    f16* dst = Gdn + ((size_t)b * DD + d) * NN + n0 + nh;
#pragma unroll
    for (int k = 0; k < 4; ++k)
      *(half8*)(dst + k * 8) = *(const half8*)(tmp + k * 8);
  }
}

// ---------- flash attention: 2 q-tiles/wave, KVBLK=32, KV-split x5 ----------
// 1280 blocks (b = bid&7 -> XCD pin; 5 blocks/CU resident = LDS ceiling, 20 waves/CU),
// 4 waves/block, 32 q/wave. Same proven iteration body as the 93us Round-11 kernel;
// only the split arithmetic changed (tile-parameter change, inherits verification).
// Splits own 26/26/26/25/25 key-tiles; outputs UNNORMALIZED f16 acc + (m,l);
// 5-way merge fused into k_gemm2.
__global__ __launch_bounds__(256, 3) void k_flash(const f16* __restrict__ T, const f16* __restrict__ P,
                                                  const f16* __restrict__ Gdn, f16* __restrict__ accs,
                                                  float* __restrict__ ml) {
  __shared__ char smem[32768];
  int bid = blockIdx.x;
  int b = bid & 7;
  int u = bid >> 3;      // 0..159
  int hf = u % NSPLIT;   // split 0..4
  int qx = u / NSPLIT;   // 0..31
  int t0 = (hf <= 2) ? hf * 26 : 78 + (hf - 3) * 25;  // first key-tile
  int nt = (hf <= 2) ? 26 : 25;                       // tiles in this split
  int tid = threadIdx.x;
  int lane = tid & 63, wave = tid >> 6;
  int lr = lane & 15, lg = lane >> 4;
  int q0 = qx * 128 + wave * 32;  // two tiles: q0..q0+15, q0+16..q0+31
  const f16* Tb = T + (size_t)b * NN * DD;
  const f16* Pb = P + ((size_t)b * NN + t0 * 32) * DD;
  const f16* Vb = Gdn + (size_t)b * DD * NN + t0 * 32;
  int srcq = 4 * lg;

  // hoisted staging bases
  const f16* kbase[2];
  const f16* vbase[2];
  char* kdst[2];
  char* vdst[2];
#pragma unroll
  for (int inst = 0; inst < 2; ++inst) {
    int t = inst * 256 + tid;
    int row = t >> 4, sp = t & 15, sl = sp ^ (row & 7);
    kbase[inst] = Pb + (size_t)PERM32(row) * DD + sl * 8;
    kdst[inst] = smem + (inst * 256 + wave * 64) * 16;
    int dv = t >> 2, gv = t & 3, glv = gv ^ ((dv >> 1) & 3);
    vbase[inst] = Vb + (size_t)dv * NN + glv * 8;
    vdst[inst] = smem + 16384 + (inst * 256 + wave * 64) * 16;
  }

  half8 qf[2][4];
  for (int qt = 0; qt < 2; ++qt)
    for (int ks = 0; ks < 4; ++ks) {
      half8 v = *(const half8*)(Tb + (size_t)(q0 + qt * 16 + lr) * DD + ks * 32 + lg * 8);
      for (int j = 0; j < 8; ++j) v[j] *= (f16)1.44269504f;  // log2(e) into Q
      qf[qt][ks] = v;
    }
  half8 ones;
  for (int j = 0; j < 8; ++j) ones[j] = (f16)1.f;

  f32x4 acc[2][8] = {};
  f32x4 lsum[2] = {};
  float m_run[2] = {-1e30f, -1e30f};

  // prologue: K(0), V(0)
#pragma unroll
  for (int inst = 0; inst < 2; ++inst) gload_lds16(kbase[inst], kdst[inst]);
#pragma unroll
  for (int inst = 0; inst < 2; ++inst) gload_lds16(vbase[inst], vdst[inst]);

  for (int kb = 0; kb < nt; ++kb) {
    int keyn = (kb < nt - 1) ? kb * 32 + 32 : 0;  // last prefetch harmless
    int cur = (kb & 1) * 8192, nxt = ((kb + 1) & 1) * 8192;
    char* Kc = smem + cur;
    char* Vc = smem + 16384 + cur;

    // issue K(kb+1)
    size_t ko = (size_t)keyn * DD;
#pragma unroll
    for (int inst = 0; inst < 2; ++inst) gload_lds16(kbase[inst] + ko, kdst[inst] + nxt);
    asm volatile("s_waitcnt vmcnt(4)" ::: "memory");  // K(kb) done; V(kb)+K(kb+1) in flight
    __builtin_amdgcn_sched_barrier(0);
    __builtin_amdgcn_s_barrier();  // B1
    __builtin_amdgcn_sched_barrier(0);

    // QK^T swapped, kf shared by both q-tiles
    f32x4 s[2][2];
    __builtin_amdgcn_s_setprio(1);
    for (int kt = 0; kt < 2; ++kt) {
      half8 kf[4];
      for (int ks = 0; ks < 4; ++ks)
        kf[ks] = *(const half8*)(Kc + (kt * 16 + lr) * 256 + (((ks * 4 + lg) ^ (lr & 7)) << 4));
      for (int qt = 0; qt < 2; ++qt) {
        f32x4 t = {};
        for (int ks = 0; ks < 4; ++ks) t = mfma16(kf[ks], qf[qt][ks], t);
        s[qt][kt] = t;
      }
    }
    __builtin_amdgcn_s_setprio(0);

    // two independent softmax chains (defer-max THR = 11.5 log2-units)
    half8 af[2];
    for (int qt = 0; qt < 2; ++qt) {
      float mx = fmaxf(fmaxf(s[qt][0][0], s[qt][0][1]), fmaxf(s[qt][0][2], s[qt][0][3]));
      mx = fmaxf(mx, fmaxf(fmaxf(s[qt][1][0], s[qt][1][1]), fmaxf(s[qt][1][2], s[qt][1][3])));
      mx = fmaxf(mx, __shfl_xor(mx, 16));
      mx = fmaxf(mx, __shfl_xor(mx, 32));
      bool grow = mx > m_run[qt] + 11.5f;
      if (__ballot(grow)) {
        float mn = fmaxf(m_run[qt], mx);
        float corr = EXP2(m_run[qt] - mn);
        m_run[qt] = mn;
        float c0 = __shfl(corr, srcq + 0), c1 = __shfl(corr, srcq + 1);
        float c2 = __shfl(corr, srcq + 2), c3 = __shfl(corr, srcq + 3);
        lsum[qt][0] *= c0; lsum[qt][1] *= c1; lsum[qt][2] *= c2; lsum[qt][3] *= c3;
        for (int nb = 0; nb < 8; ++nb) {
          acc[qt][nb][0] *= c0; acc[qt][nb][1] *= c1;
          acc[qt][nb][2] *= c2; acc[qt][nb][3] *= c3;
        }
      }
      for (int kt = 0; kt < 2; ++kt)
        for (int r = 0; r < 4; ++r)
          s[qt][kt][r] = EXP2(s[qt][kt][r] - m_run[qt]);
      union { half8 h8; half2t h2[4]; } un;
      un.h2[0] = pkrtz(s[qt][0][0], s[qt][0][1]);
      un.h2[1] = pkrtz(s[qt][0][2], s[qt][0][3]);
      un.h2[2] = pkrtz(s[qt][1][0], s[qt][1][1]);
      un.h2[3] = pkrtz(s[qt][1][2], s[qt][1][3]);
      af[qt] = un.h8;
      lsum[qt] = mfma16(af[qt], ones, lsum[qt]);
    }

    // issue V(kb+1)
#pragma unroll
    for (int inst = 0; inst < 2; ++inst) gload_lds16(vbase[inst] + keyn, vdst[inst] + nxt);
    asm volatile("s_waitcnt vmcnt(4)" ::: "memory");  // V(kb) done; K/V(kb+1) in flight
    __builtin_amdgcn_sched_barrier(0);
    __builtin_amdgcn_s_barrier();  // B2
    __builtin_amdgcn_sched_barrier(0);

    // PV: vf read once, both q-tiles consume
    __builtin_amdgcn_s_setprio(1);
    for (int nb = 0; nb < 8; ++nb) {
      int d = nb * 16 + lr;
      half8 vf = *(const half8*)(Vc + d * 64 + ((lg ^ ((d >> 1) & 3)) << 4));
      acc[0][nb] = mfma16(af[0], vf, acc[0][nb]);
      acc[1][nb] = mfma16(af[1], vf, acc[1][nb]);
    }
    __builtin_amdgcn_s_setprio(0);
  }
  asm volatile("s_waitcnt vmcnt(0)" ::: "memory");

  // epilogue: unnormalized acc + (m, l)
  size_t gq0 = (size_t)b * NN + q0;
  f16* A = accs + (size_t)hf * ((size_t)BB * NN * DD) + gq0 * DD;
  for (int qt = 0; qt < 2; ++qt)
    for (int nb = 0; nb < 8; ++nb)
      for (int r = 0; r < 4; ++r)
        A[(size_t)(qt * 16 + lg * 4 + r) * DD + nb * 16 + lr] = (f16)acc[qt][nb][r];
  float* mArr = ml + hf * 32768;
  float* lArr = ml + NSPLIT * 32768 + hf * 32768;
  if (lg == 0) {
    mArr[gq0 + lr] = m_run[0];
    mArr[gq0 + 16 + lr] = m_run[1];
  }
  if (lr == 0)
    for (int r = 0; r < 4; ++r) {
      lArr[gq0 + lg * 4 + r] = lsum[0][r];
      lArr[gq0 + 16 + lg * 4 + r] = lsum[1][r];
    }
}

// ---------- output projection + fused 5-way merge + BN stats ----------
// 256 blocks, each owns 128 rows (2 mt-tiles of 64), all 256 output channels.
// A read once globally (40 MB); W (64KB) L2-resident; full CU coverage.
__global__ __launch_bounds__(256) void k_gemm2(const f16* __restrict__ Y, const float* __restrict__ ml,
                                               const f16* __restrict__ Wwh, const float* __restrict__ wb,
                                               f16* __restrict__ wy, float* __restrict__ stats) {
  __shared__ float part[2][8][256];  // 16 KB
  const size_t SEG = (size_t)BB * NN * DD;
  int lane = threadIdx.x & 63, wave = threadIdx.x >> 6;
  int lr = lane & 15, lg = lane >> 4;
  int wr = wave >> 1, wc = wave & 1;
  float ps[4][2][2] = {};  // [yb][j][sum,sumsq]
  for (int mt = 0; mt < 2; ++mt) {
    int m0 = (blockIdx.x * 2 + mt) * 64 + wr * 32;
    // per-lane merge scales for rows m0+lr (i=0), m0+16+lr (i=1)
    f16 ch[2][NSPLIT];
    for (int i = 0; i < 2; ++i) {
      int row = m0 + i * 16 + lr;
      float m[NSPLIT], l[NSPLIT];
      float mm = -1e30f;
      for (int s = 0; s < NSPLIT; ++s) {
        m[s] = ml[s * 32768 + row];
        l[s] = ml[NSPLIT * 32768 + s * 32768 + row];
        mm = fmaxf(mm, m[s]);
      }
      float den = 0.f, c[NSPLIT];
      for (int s = 0; s < NSPLIT; ++s) {
        c[s] = EXP2(m[s] - mm);
        den += l[s] * c[s];
      }
      float inv = 1.f / den;
      for (int s = 0; s < NSPLIT; ++s) ch[i][s] = (f16)(c[s] * inv);
    }
    // merged A-fragments (read once per row)
    half8 a[2][4];
    for (int i = 0; i < 2; ++i)
      for (int k0 = 0; k0 < 4; ++k0) {
        size_t off = (size_t)(m0 + i * 16 + lr) * DD + k0 * 32 + lg * 8;
        half8 acc8 = *(const half8*)(Y + off) * ch[i][0];
        for (int s = 1; s < NSPLIT; ++s)
          acc8 = acc8 + *(const half8*)(Y + s * SEG + off) * ch[i][s];
        a[i][k0] = acc8;
      }
    for (int yb = 0; yb < 4; ++yb) {
      int c0 = yb * 64 + wc * 32;
      f32x4 acc[2][2] = {};
      for (int k0 = 0; k0 < 4; ++k0) {
        half8 w[2];
        for (int j = 0; j < 2; ++j)
          w[j] = *(const half8*)(Wwh + (size_t)(c0 + j * 16 + lr) * DD + k0 * 32 + lg * 8);
        for (int i = 0; i < 2; ++i)
          for (int j = 0; j < 2; ++j)
            acc[i][j] = mfma16(a[i][k0], w[j], acc[i][j]);
      }
      for (int i = 0; i < 2; ++i)
        for (int j = 0; j < 2; ++j) {
          float bias = wb[c0 + j * 16 + lr];
          for (int r = 0; r < 4; ++r) {
            int row = m0 + i * 16 + lg * 4 + r;
            int col = c0 + j * 16 + lr;
            float v = acc[i][j][r] + bias;
            wy[(size_t)row * CC + col] = (f16)v;
            ps[yb][j][0] += v;
            ps[yb][j][1] += v * v;
          }
        }
    }
  }
  for (int yb = 0; yb < 4; ++yb)
    for (int j = 0; j < 2; ++j) {
      int col = yb * 64 + wc * 32 + j * 16 + lr;
      part[0][wr * 4 + lg][col] = ps[yb][j][0];
      part[1][wr * 4 + lg][col] = ps[yb][j][1];
    }
  __syncthreads();
  {
    int col = threadIdx.x;
    for (int metric = 0; metric < 2; ++metric) {
      float s = 0.f;
      for (int wtr = 0; wtr < 8; ++wtr) s += part[metric][wtr][col];
      atomicAdd(&stats[metric * CC + col], s);
    }
  }
}

// ---------- BN apply + residual ----------
__global__ void k_bn_apply(const f16* __restrict__ wy, const float* __restrict__ x,
                           const float* __restrict__ stats, const float* __restrict__ gamma,
                           const float* __restrict__ beta, float* __restrict__ out) {
  __shared__ f16 tile[32][33];
  int b = blockIdx.z, c0 = blockIdx.y * 32, n0 = blockIdx.x * 32;
  int tx = threadIdx.x, ty = threadIdx.y;
  for (int j = 0; j < 4; ++j) {
    int nn = ty + j * 8;
    tile[nn][tx] = wy[((size_t)b * NN + n0 + nn) * CC + c0 + tx];
  }
  __syncthreads();
  const float inv_cnt = 1.f / (float)(BB * NN);
  for (int j = 0; j < 4; ++j) {
    int cc = ty + j * 8;
    int c = c0 + cc;
    float mean = stats[c] * inv_cnt;
    float var = stats[CC + c] * inv_cnt - mean * mean;
    float scale = gamma[c] * rsqrtf(var + BN_EPS);
    size_t oi = ((size_t)b * CC + c) * NN + n0 + tx;
    out[oi] = ((float)tile[tx][cc] - mean) * scale + beta[c] + x[oi];
  }
}

extern "C" void kernel_launch(void* const* d_in, const int* in_sizes, int n_in,
                              void* d_out, int out_size, void* d_ws, size_t ws_size,
                              hipStream_t stream) {
  const float* x = (const float*)d_in[0];
  const float* tw = (const float*)d_in[1];
  const float* pw = (const float*)d_in[2];
  const float* gw = (const float*)d_in[3];
  const float* ww = (const float*)d_in[4];
  const float* wb = (const float*)d_in[5];
  const float* gamma = (const float*)d_in[6];
  const float* beta = (const float*)d_in[7];
  float* out = (float*)d_out;
  char* ws = (char*)d_ws;

  f16* Wcat = (f16*)(ws + 0);                 // 192 KB
  f16* Wwh = (f16*)(ws + 196608);             // 64 KB
  float* stats = (float*)(ws + 262144);       // 2 KB
  float* ml = (float*)(ws + 524288);          // 1.25 MB: m[5][32768], l[5][32768]
  const size_t BASE = 1 << 21;                // 2 MB
  f16* T = (f16*)(ws + BASE);                 // 8 MB
  f16* P = (f16*)(ws + BASE + 8388608);       // 8 MB
  f16* Gdn = (f16*)(ws + BASE + 16777216);    // 8 MB
  f16* accs = (f16*)(ws + BASE + 25165824);   // 5 x 8 MB unnormalized splits
  f16* wy = (f16*)(ws + BASE);                // 16 MB (reuses dead T+P region)

  k_cast_weights<<<512, 256, 0, stream>>>(tw, pw, gw, ww, Wcat, Wwh, stats);
  k_gemm1<<<dim3(NN / 64, BB), 256, 0, stream>>>(x, Wcat, T, P, Gdn);
  k_flash<<<1280, 256, 0, stream>>>(T, P, Gdn, accs, ml);
  k_gemm2<<<256, 256, 0, stream>>>(accs, ml, Wwh, wb, wy, stats);
  k_bn_apply<<<dim3(NN / 32, CC / 32, BB), dim3(32, 8), 0, stream>>>(wy, x, stats, gamma, beta, out);
}

// Round 17
// 167.325 us; speedup vs baseline: 1.0357x; 1.0357x over previous
//
#include <hip/hip_runtime.h>

#define BB 8
#define CC 256
#define DD 128
#define NN 4096
#define BN_EPS 1e-5f
#define NSPLIT 4

typedef _Float16 f16;
typedef _Float16 half8 __attribute__((ext_vector_type(8)));
typedef _Float16 half2t __attribute__((ext_vector_type(2)));
typedef float f32x4 __attribute__((ext_vector_type(4)));

__device__ __forceinline__ f32x4 mfma16(half8 a, half8 b, f32x4 c) {
  return __builtin_amdgcn_mfma_f32_16x16x32_f16(a, b, c, 0, 0, 0);
}

__device__ __forceinline__ void gload_lds16(const void* g, void* l) {
  __builtin_amdgcn_global_load_lds((const __attribute__((address_space(1))) void*)g,
                                   (__attribute__((address_space(3))) void*)l, 16, 0, 0);
}

__device__ __forceinline__ half2t pkrtz(float a, float b) {
  auto t = __builtin_amdgcn_cvt_pkrtz(a, b);
  return __builtin_bit_cast(half2t, t);
}

#define EXP2(x) __builtin_amdgcn_exp2f(x)

// key permutation for 32-key tiles: swapped-QK register layout feeds PV A-frag directly.
#define PERM32(i) ((((i) >> 2) & 3) * 8 + (((i) >> 4) & 1) * 4 + ((i) & 3))

// ---------- weights cast (fp32 -> fp16), stats zero ----------
__global__ void k_cast_weights(const float* __restrict__ tw, const float* __restrict__ pw,
                               const float* __restrict__ gw, const float* __restrict__ ww,
                               f16* __restrict__ Wcat, f16* __restrict__ Wwh,
                               float* __restrict__ stats) {
  int i = blockIdx.x * 256 + threadIdx.x;
  if (i < 32768) Wcat[i] = (f16)tw[i];
  else if (i < 65536) Wcat[i] = (f16)pw[i - 32768];
  else if (i < 98304) Wcat[i] = (f16)gw[i - 65536];
  else if (i < 131072) Wwh[i - 98304] = (f16)ww[i - 98304];
  if (i < 512) stats[i] = 0.f;
}

// ---------- fused projections: x staged+transposed in LDS, G transposed in LDS ----------
__global__ __launch_bounds__(256) void k_gemm1(const float* __restrict__ x, const f16* __restrict__ Wcat,
                                               f16* __restrict__ T, f16* __restrict__ P,
                                               f16* __restrict__ Gdn) {
  __shared__ char xls[32768];  // xl[n 64][c 256] f16, granule-swizzled
  __shared__ char gls[16384];  // gl[n 64][d 128] f16, granule-swizzled
  int b = blockIdx.y;
  int n0 = blockIdx.x * 64;
  int tid = threadIdx.x;
  int lane = tid & 63, wave = tid >> 6;
  int lr = lane & 15, lg = lane >> 4;
  int wr = wave >> 1, wc = wave & 1;

  {
    int c = tid;
    const float* src = x + ((size_t)b * CC + c) * NN + n0;
#pragma unroll
    for (int n4 = 0; n4 < 64; n4 += 4) {
      f32x4 v = *(const f32x4*)(src + n4);
#pragma unroll
      for (int k = 0; k < 4; ++k) {
        int n = n4 + k;
        *(f16*)(xls + n * 512 + ((((c >> 3) ^ (n & 7)) * 8 + (c & 7)) * 2)) = (f16)v[k];
      }
    }
  }
  __syncthreads();

  half8 a[2][8];
#pragma unroll
  for (int i = 0; i < 2; ++i) {
    int nloc = wr * 32 + i * 16 + lr;
#pragma unroll
    for (int k0 = 0; k0 < 8; ++k0)
      a[i][k0] = *(const half8*)(xls + nloc * 512 + (((k0 * 4 + lg) ^ (nloc & 7)) << 4));
  }

  size_t base = (size_t)b * NN + n0;
#pragma unroll
  for (int yb = 0; yb < 6; ++yb) {
    int c0 = yb * 64 + wc * 32;
    f32x4 acc[2][2] = {};
#pragma unroll
    for (int k0 = 0; k0 < 8; ++k0) {
      half8 w[2];
      for (int j = 0; j < 2; ++j)
        w[j] = *(const half8*)(Wcat + (size_t)(c0 + j * 16 + lr) * CC + k0 * 32 + lg * 8);
      for (int i = 0; i < 2; ++i)
        for (int j = 0; j < 2; ++j)
          acc[i][j] = mfma16(a[i][k0], w[j], acc[i][j]);
    }
    if (yb < 4) {
      f16* dst = (yb < 2) ? T : P;
      int cl0 = (yb & 1) * 64 + wc * 32;
      for (int i = 0; i < 2; ++i)
        for (int j = 0; j < 2; ++j)
          for (int r = 0; r < 4; ++r) {
            int row = wr * 32 + i * 16 + lg * 4 + r;
            int col = cl0 + j * 16 + lr;
            dst[(base + row) * DD + col] = (f16)acc[i][j][r];
          }
    } else {
      for (int i = 0; i < 2; ++i)
        for (int j = 0; j < 2; ++j)
          for (int r = 0; r < 4; ++r) {
            int n = wr * 32 + i * 16 + lg * 4 + r;
            int d = (yb - 4) * 64 + wc * 32 + j * 16 + lr;
            *(f16*)(gls + n * 256 + ((((d >> 3) ^ (n & 7)) * 8 + (d & 7)) * 2)) = (f16)acc[i][j][r];
          }
    }
  }
  __syncthreads();
  {
    int d = tid >> 1, nh = (tid & 1) * 32;
    f16 tmp[32];
#pragma unroll
    for (int k = 0; k < 32; ++k) {
      int n = nh + k;
      tmp[k] = *(const f16*)(gls + n * 256 + ((((d >> 3) ^ (n & 7)) * 8 + (d & 7)) * 2));
    }
    f16* dst = Gdn + ((size_t)b * DD + d) * NN + n0 + nh;
#pragma unroll
    for (int k = 0; k < 4; ++k)
      *(half8*)(dst + k * 8) = *(const half8*)(tmp + k * 8);
  }
}

// ---------- flash attention: 2 q-tiles/wave, KVBLK=32, KV-split x4 ----------
// 1024 blocks (b = bid&7 -> XCD pin; 4 blocks/CU = 128KB LDS, co-residency proven in R9),
// 4 waves/block, 32 q/wave. Iteration body identical to the proven Round-11 kernel;
// splits own exactly 32 key-tiles each (no tail). Outputs UNNORMALIZED f16 acc + (m,l);
// 4-way merge fused into k_gemm2.
__global__ __launch_bounds__(256, 3) void k_flash(const f16* __restrict__ T, const f16* __restrict__ P,
                                                  const f16* __restrict__ Gdn, f16* __restrict__ accs,
                                                  float* __restrict__ ml) {
  __shared__ char smem[32768];
  int bid = blockIdx.x;
  int b = bid & 7;
  int u = bid >> 3;      // 0..127
  int hf = u & 3;        // split 0..3
  int qx = u >> 2;       // 0..31
  int t0 = hf * 32;      // first key-tile
  const int nt = 32;     // tiles per split
  int tid = threadIdx.x;
  int lane = tid & 63, wave = tid >> 6;
  int lr = lane & 15, lg = lane >> 4;
  int q0 = qx * 128 + wave * 32;  // two tiles: q0..q0+15, q0+16..q0+31
  const f16* Tb = T + (size_t)b * NN * DD;
  const f16* Pb = P + ((size_t)b * NN + t0 * 32) * DD;
  const f16* Vb = Gdn + (size_t)b * DD * NN + t0 * 32;
  int srcq = 4 * lg;

  // hoisted staging bases
  const f16* kbase[2];
  const f16* vbase[2];
  char* kdst[2];
  char* vdst[2];
#pragma unroll
  for (int inst = 0; inst < 2; ++inst) {
    int t = inst * 256 + tid;
    int row = t >> 4, sp = t & 15, sl = sp ^ (row & 7);
    kbase[inst] = Pb + (size_t)PERM32(row) * DD + sl * 8;
    kdst[inst] = smem + (inst * 256 + wave * 64) * 16;
    int dv = t >> 2, gv = t & 3, glv = gv ^ ((dv >> 1) & 3);
    vbase[inst] = Vb + (size_t)dv * NN + glv * 8;
    vdst[inst] = smem + 16384 + (inst * 256 + wave * 64) * 16;
  }

  half8 qf[2][4];
  for (int qt = 0; qt < 2; ++qt)
    for (int ks = 0; ks < 4; ++ks) {
      half8 v = *(const half8*)(Tb + (size_t)(q0 + qt * 16 + lr) * DD + ks * 32 + lg * 8);
      for (int j = 0; j < 8; ++j) v[j] *= (f16)1.44269504f;  // log2(e) into Q
      qf[qt][ks] = v;
    }
  half8 ones;
  for (int j = 0; j < 8; ++j) ones[j] = (f16)1.f;

  f32x4 acc[2][8] = {};
  f32x4 lsum[2] = {};
  float m_run[2] = {-1e30f, -1e30f};

  // prologue: K(0), V(0)
#pragma unroll
  for (int inst = 0; inst < 2; ++inst) gload_lds16(kbase[inst], kdst[inst]);
#pragma unroll
  for (int inst = 0; inst < 2; ++inst) gload_lds16(vbase[inst], vdst[inst]);

  for (int kb = 0; kb < nt; ++kb) {
    int keyn = (kb < nt - 1) ? kb * 32 + 32 : 0;  // last prefetch harmless
    int cur = (kb & 1) * 8192, nxt = ((kb + 1) & 1) * 8192;
    char* Kc = smem + cur;
    char* Vc = smem + 16384 + cur;

    // issue K(kb+1)
    size_t ko = (size_t)keyn * DD;
#pragma unroll
    for (int inst = 0; inst < 2; ++inst) gload_lds16(kbase[inst] + ko, kdst[inst] + nxt);
    asm volatile("s_waitcnt vmcnt(4)" ::: "memory");  // K(kb) done; V(kb)+K(kb+1) in flight
    __builtin_amdgcn_sched_barrier(0);
    __builtin_amdgcn_s_barrier();  // B1
    __builtin_amdgcn_sched_barrier(0);

    // QK^T swapped, kf shared by both q-tiles
    f32x4 s[2][2];
    __builtin_amdgcn_s_setprio(1);
    for (int kt = 0; kt < 2; ++kt) {
      half8 kf[4];
      for (int ks = 0; ks < 4; ++ks)
        kf[ks] = *(const half8*)(Kc + (kt * 16 + lr) * 256 + (((ks * 4 + lg) ^ (lr & 7)) << 4));
      for (int qt = 0; qt < 2; ++qt) {
        f32x4 t = {};
        for (int ks = 0; ks < 4; ++ks) t = mfma16(kf[ks], qf[qt][ks], t);
        s[qt][kt] = t;
      }
    }
    __builtin_amdgcn_s_setprio(0);

    // two independent softmax chains (defer-max THR = 11.5 log2-units)
    half8 af[2];
    for (int qt = 0; qt < 2; ++qt) {
      float mx = fmaxf(fmaxf(s[qt][0][0], s[qt][0][1]), fmaxf(s[qt][0][2], s[qt][0][3]));
      mx = fmaxf(mx, fmaxf(fmaxf(s[qt][1][0], s[qt][1][1]), fmaxf(s[qt][1][2], s[qt][1][3])));
      mx = fmaxf(mx, __shfl_xor(mx, 16));
      mx = fmaxf(mx, __shfl_xor(mx, 32));
      bool grow = mx > m_run[qt] + 11.5f;
      if (__ballot(grow)) {
        float mn = fmaxf(m_run[qt], mx);
        float corr = EXP2(m_run[qt] - mn);
        m_run[qt] = mn;
        float c0 = __shfl(corr, srcq + 0), c1 = __shfl(corr, srcq + 1);
        float c2 = __shfl(corr, srcq + 2), c3 = __shfl(corr, srcq + 3);
        lsum[qt][0] *= c0; lsum[qt][1] *= c1; lsum[qt][2] *= c2; lsum[qt][3] *= c3;
        for (int nb = 0; nb < 8; ++nb) {
          acc[qt][nb][0] *= c0; acc[qt][nb][1] *= c1;
          acc[qt][nb][2] *= c2; acc[qt][nb][3] *= c3;
        }
      }
      for (int kt = 0; kt < 2; ++kt)
        for (int r = 0; r < 4; ++r)
          s[qt][kt][r] = EXP2(s[qt][kt][r] - m_run[qt]);
      union { half8 h8; half2t h2[4]; } un;
      un.h2[0] = pkrtz(s[qt][0][0], s[qt][0][1]);
      un.h2[1] = pkrtz(s[qt][0][2], s[qt][0][3]);
      un.h2[2] = pkrtz(s[qt][1][0], s[qt][1][1]);
      un.h2[3] = pkrtz(s[qt][1][2], s[qt][1][3]);
      af[qt] = un.h8;
      lsum[qt] = mfma16(af[qt], ones, lsum[qt]);
    }

    // issue V(kb+1)
#pragma unroll
    for (int inst = 0; inst < 2; ++inst) gload_lds16(vbase[inst] + keyn, vdst[inst] + nxt);
    asm volatile("s_waitcnt vmcnt(4)" ::: "memory");  // V(kb) done; K/V(kb+1) in flight
    __builtin_amdgcn_sched_barrier(0);
    __builtin_amdgcn_s_barrier();  // B2
    __builtin_amdgcn_sched_barrier(0);

    // PV: vf read once, both q-tiles consume
    __builtin_amdgcn_s_setprio(1);
    for (int nb = 0; nb < 8; ++nb) {
      int d = nb * 16 + lr;
      half8 vf = *(const half8*)(Vc + d * 64 + ((lg ^ ((d >> 1) & 3)) << 4));
      acc[0][nb] = mfma16(af[0], vf, acc[0][nb]);
      acc[1][nb] = mfma16(af[1], vf, acc[1][nb]);
    }
    __builtin_amdgcn_s_setprio(0);
  }
  asm volatile("s_waitcnt vmcnt(0)" ::: "memory");

  // epilogue: unnormalized acc + (m, l)
  size_t gq0 = (size_t)b * NN + q0;
  f16* A = accs + (size_t)hf * ((size_t)BB * NN * DD) + gq0 * DD;
  for (int qt = 0; qt < 2; ++qt)
    for (int nb = 0; nb < 8; ++nb)
      for (int r = 0; r < 4; ++r)
        A[(size_t)(qt * 16 + lg * 4 + r) * DD + nb * 16 + lr] = (f16)acc[qt][nb][r];
  float* mArr = ml + hf * 32768;
  float* lArr = ml + NSPLIT * 32768 + hf * 32768;
  if (lg == 0) {
    mArr[gq0 + lr] = m_run[0];
    mArr[gq0 + 16 + lr] = m_run[1];
  }
  if (lr == 0)
    for (int r = 0; r < 4; ++r) {
      lArr[gq0 + lg * 4 + r] = lsum[0][r];
      lArr[gq0 + 16 + lg * 4 + r] = lsum[1][r];
    }
}

// ---------- output projection + fused 4-way merge + BN stats ----------
// 256 blocks, each owns 128 rows (2 mt-tiles of 64), all 256 output channels.
// A read once globally (32 MB); W (64KB) L2-resident; full CU coverage.
__global__ __launch_bounds__(256) void k_gemm2(const f16* __restrict__ Y, const float* __restrict__ ml,
                                               const f16* __restrict__ Wwh, const float* __restrict__ wb,
                                               f16* __restrict__ wy, float* __restrict__ stats) {
  __shared__ float part[2][8][256];  // 16 KB
  const size_t SEG = (size_t)BB * NN * DD;
  int lane = threadIdx.x & 63, wave = threadIdx.x >> 6;
  int lr = lane & 15, lg = lane >> 4;
  int wr = wave >> 1, wc = wave & 1;
  float ps[4][2][2] = {};  // [yb][j][sum,sumsq]
  for (int mt = 0; mt < 2; ++mt) {
    int m0 = (blockIdx.x * 2 + mt) * 64 + wr * 32;
    // per-lane merge scales for rows m0+lr (i=0), m0+16+lr (i=1)
    f16 ch[2][NSPLIT];
    for (int i = 0; i < 2; ++i) {
      int row = m0 + i * 16 + lr;
      float m[NSPLIT], l[NSPLIT];
      float mm = -1e30f;
      for (int s = 0; s < NSPLIT; ++s) {
        m[s] = ml[s * 32768 + row];
        l[s] = ml[NSPLIT * 32768 + s * 32768 + row];
        mm = fmaxf(mm, m[s]);
      }
      float den = 0.f, c[NSPLIT];
      for (int s = 0; s < NSPLIT; ++s) {
        c[s] = EXP2(m[s] - mm);
        den += l[s] * c[s];
      }
      float inv = 1.f / den;
      for (int s = 0; s < NSPLIT; ++s) ch[i][s] = (f16)(c[s] * inv);
    }
    // merged A-fragments (read once per row)
    half8 a[2][4];
    for (int i = 0; i < 2; ++i)
      for (int k0 = 0; k0 < 4; ++k0) {
        size_t off = (size_t)(m0 + i * 16 + lr) * DD + k0 * 32 + lg * 8;
        half8 acc8 = *(const half8*)(Y + off) * ch[i][0];
        for (int s = 1; s < NSPLIT; ++s)
          acc8 = acc8 + *(const half8*)(Y + s * SEG + off) * ch[i][s];
        a[i][k0] = acc8;
      }
    for (int yb = 0; yb < 4; ++yb) {
      int c0 = yb * 64 + wc * 32;
      f32x4 acc[2][2] = {};
      for (int k0 = 0; k0 < 4; ++k0) {
        half8 w[2];
        for (int j = 0; j < 2; ++j)
          w[j] = *(const half8*)(Wwh + (size_t)(c0 + j * 16 + lr) * DD + k0 * 32 + lg * 8);
        for (int i = 0; i < 2; ++i)
          for (int j = 0; j < 2; ++j)
            acc[i][j] = mfma16(a[i][k0], w[j], acc[i][j]);
      }
      for (int i = 0; i < 2; ++i)
        for (int j = 0; j < 2; ++j) {
          float bias = wb[c0 + j * 16 + lr];
          for (int r = 0; r < 4; ++r) {
            int row = m0 + i * 16 + lg * 4 + r;
            int col = c0 + j * 16 + lr;
            float v = acc[i][j][r] + bias;
            wy[(size_t)row * CC + col] = (f16)v;
            ps[yb][j][0] += v;
            ps[yb][j][1] += v * v;
          }
        }
    }
  }
  for (int yb = 0; yb < 4; ++yb)
    for (int j = 0; j < 2; ++j) {
      int col = yb * 64 + wc * 32 + j * 16 + lr;
      part[0][wr * 4 + lg][col] = ps[yb][j][0];
      part[1][wr * 4 + lg][col] = ps[yb][j][1];
    }
  __syncthreads();
  {
    int col = threadIdx.x;
    for (int metric = 0; metric < 2; ++metric) {
      float s = 0.f;
      for (int wtr = 0; wtr < 8; ++wtr) s += part[metric][wtr][col];
      atomicAdd(&stats[metric * CC + col], s);
    }
  }
}

// ---------- BN apply + residual ----------
__global__ void k_bn_apply(const f16* __restrict__ wy, const float* __restrict__ x,
                           const float* __restrict__ stats, const float* __restrict__ gamma,
                           const float* __restrict__ beta, float* __restrict__ out) {
  __shared__ f16 tile[32][33];
  int b = blockIdx.z, c0 = blockIdx.y * 32, n0 = blockIdx.x * 32;
  int tx = threadIdx.x, ty = threadIdx.y;
  for (int j = 0; j < 4; ++j) {
    int nn = ty + j * 8;
    tile[nn][tx] = wy[((size_t)b * NN + n0 + nn) * CC + c0 + tx];
  }
  __syncthreads();
  const float inv_cnt = 1.f / (float)(BB * NN);
  for (int j = 0; j < 4; ++j) {
    int cc = ty + j * 8;
    int c = c0 + cc;
    float mean = stats[c] * inv_cnt;
    float var = stats[CC + c] * inv_cnt - mean * mean;
    float scale = gamma[c] * rsqrtf(var + BN_EPS);
    size_t oi = ((size_t)b * CC + c) * NN + n0 + tx;
    out[oi] = ((float)tile[tx][cc] - mean) * scale + beta[c] + x[oi];
  }
}

extern "C" void kernel_launch(void* const* d_in, const int* in_sizes, int n_in,
                              void* d_out, int out_size, void* d_ws, size_t ws_size,
                              hipStream_t stream) {
  const float* x = (const float*)d_in[0];
  const float* tw = (const float*)d_in[1];
  const float* pw = (const float*)d_in[2];
  const float* gw = (const float*)d_in[3];
  const float* ww = (const float*)d_in[4];
  const float* wb = (const float*)d_in[5];
  const float* gamma = (const float*)d_in[6];
  const float* beta = (const float*)d_in[7];
  float* out = (float*)d_out;
  char* ws = (char*)d_ws;

  f16* Wcat = (f16*)(ws + 0);                 // 192 KB
  f16* Wwh = (f16*)(ws + 196608);             // 64 KB
  float* stats = (float*)(ws + 262144);       // 2 KB
  float* ml = (float*)(ws + 524288);          // 1 MB: m[4][32768], l[4][32768]
  const size_t BASE = 1 << 21;                // 2 MB
  f16* T = (f16*)(ws + BASE);                 // 8 MB
  f16* P = (f16*)(ws + BASE + 8388608);       // 8 MB
  f16* Gdn = (f16*)(ws + BASE + 16777216);    // 8 MB
  f16* accs = (f16*)(ws + BASE + 25165824);   // 4 x 8 MB unnormalized splits
  f16* wy = (f16*)(ws + BASE);                // 16 MB (reuses dead T+P region)

  k_cast_weights<<<512, 256, 0, stream>>>(tw, pw, gw, ww, Wcat, Wwh, stats);
  k_gemm1<<<dim3(NN / 64, BB), 256, 0, stream>>>(x, Wcat, T, P, Gdn);
  k_flash<<<1024, 256, 0, stream>>>(T, P, Gdn, accs, ml);
  k_gemm2<<<256, 256, 0, stream>>>(accs, ml, Wwh, wb, wy, stats);
  k_bn_apply<<<dim3(NN / 32, CC / 32, BB), dim3(32, 8), 0, stream>>>(wy, x, stats, gamma, beta, out);
}

// Round 18
// 161.284 us; speedup vs baseline: 1.0745x; 1.0375x over previous
//
#include <hip/hip_runtime.h>

#define BB 8
#define CC 256
#define DD 128
#define NN 4096
#define BN_EPS 1e-5f
#define NSPLIT 3

typedef _Float16 f16;
typedef _Float16 half8 __attribute__((ext_vector_type(8)));
typedef _Float16 half4 __attribute__((ext_vector_type(4)));
typedef _Float16 half2t __attribute__((ext_vector_type(2)));
typedef float f32x4 __attribute__((ext_vector_type(4)));

__device__ __forceinline__ f32x4 mfma16(half8 a, half8 b, f32x4 c) {
  return __builtin_amdgcn_mfma_f32_16x16x32_f16(a, b, c, 0, 0, 0);
}

__device__ __forceinline__ void gload_lds16(const void* g, void* l) {
  __builtin_amdgcn_global_load_lds((const __attribute__((address_space(1))) void*)g,
                                   (__attribute__((address_space(3))) void*)l, 16, 0, 0);
}

__device__ __forceinline__ half2t pkrtz(float a, float b) {
  auto t = __builtin_amdgcn_cvt_pkrtz(a, b);
  return __builtin_bit_cast(half2t, t);
}

#define EXP2(x) __builtin_amdgcn_exp2f(x)

// key permutation for 32-key tiles: swapped-QK register layout feeds PV A-frag directly.
#define PERM32(i) ((((i) >> 2) & 3) * 8 + (((i) >> 4) & 1) * 4 + ((i) & 3))

// ---------- weights cast (fp32 -> fp16), stats zero ----------
__global__ void k_cast_weights(const float* __restrict__ tw, const float* __restrict__ pw,
                               const float* __restrict__ gw, const float* __restrict__ ww,
                               f16* __restrict__ Wcat, f16* __restrict__ Wwh,
                               float* __restrict__ stats) {
  int i = blockIdx.x * 256 + threadIdx.x;
  if (i < 32768) Wcat[i] = (f16)tw[i];
  else if (i < 65536) Wcat[i] = (f16)pw[i - 32768];
  else if (i < 98304) Wcat[i] = (f16)gw[i - 65536];
  else if (i < 131072) Wwh[i - 98304] = (f16)ww[i - 98304];
  if (i < 512) stats[i] = 0.f;
}

// ---------- fused projections: x staged+transposed in LDS, G transposed in LDS ----------
__global__ __launch_bounds__(256) void k_gemm1(const float* __restrict__ x, const f16* __restrict__ Wcat,
                                               f16* __restrict__ T, f16* __restrict__ P,
                                               f16* __restrict__ Gdn) {
  __shared__ char xls[32768];  // xl[n 64][c 256] f16, granule-swizzled
  __shared__ char gls[16384];  // gl[n 64][d 128] f16, granule-swizzled
  int b = blockIdx.y;
  int n0 = blockIdx.x * 64;
  int tid = threadIdx.x;
  int lane = tid & 63, wave = tid >> 6;
  int lr = lane & 15, lg = lane >> 4;
  int wr = wave >> 1, wc = wave & 1;

  {
    int c = tid;
    const float* src = x + ((size_t)b * CC + c) * NN + n0;
#pragma unroll
    for (int n4 = 0; n4 < 64; n4 += 4) {
      f32x4 v = *(const f32x4*)(src + n4);
#pragma unroll
      for (int k = 0; k < 4; ++k) {
        int n = n4 + k;
        *(f16*)(xls + n * 512 + ((((c >> 3) ^ (n & 7)) * 8 + (c & 7)) * 2)) = (f16)v[k];
      }
    }
  }
  __syncthreads();

  half8 a[2][8];
#pragma unroll
  for (int i = 0; i < 2; ++i) {
    int nloc = wr * 32 + i * 16 + lr;
#pragma unroll
    for (int k0 = 0; k0 < 8; ++k0)
      a[i][k0] = *(const half8*)(xls + nloc * 512 + (((k0 * 4 + lg) ^ (nloc & 7)) << 4));
  }

  size_t base = (size_t)b * NN + n0;
#pragma unroll
  for (int yb = 0; yb < 6; ++yb) {
    int c0 = yb * 64 + wc * 32;
    f32x4 acc[2][2] = {};
#pragma unroll
    for (int k0 = 0; k0 < 8; ++k0) {
      half8 w[2];
      for (int j = 0; j < 2; ++j)
        w[j] = *(const half8*)(Wcat + (size_t)(c0 + j * 16 + lr) * CC + k0 * 32 + lg * 8);
      for (int i = 0; i < 2; ++i)
        for (int j = 0; j < 2; ++j)
          acc[i][j] = mfma16(a[i][k0], w[j], acc[i][j]);
    }
    if (yb < 4) {
      f16* dst = (yb < 2) ? T : P;
      int cl0 = (yb & 1) * 64 + wc * 32;
      for (int i = 0; i < 2; ++i)
        for (int j = 0; j < 2; ++j)
          for (int r = 0; r < 4; ++r) {
            int row = wr * 32 + i * 16 + lg * 4 + r;
            int col = cl0 + j * 16 + lr;
            dst[(base + row) * DD + col] = (f16)acc[i][j][r];
          }
    } else {
      for (int i = 0; i < 2; ++i)
        for (int j = 0; j < 2; ++j)
          for (int r = 0; r < 4; ++r) {
            int n = wr * 32 + i * 16 + lg * 4 + r;
            int d = (yb - 4) * 64 + wc * 32 + j * 16 + lr;
            *(f16*)(gls + n * 256 + ((((d >> 3) ^ (n & 7)) * 8 + (d & 7)) * 2)) = (f16)acc[i][j][r];
          }
    }
  }
  __syncthreads();
  {
    int d = tid >> 1, nh = (tid & 1) * 32;
    f16 tmp[32];
#pragma unroll
    for (int k = 0; k < 32; ++k) {
      int n = nh + k;
      tmp[k] = *(const f16*)(gls + n * 256 + ((((d >> 3) ^ (n & 7)) * 8 + (d & 7)) * 2));
    }
    f16* dst = Gdn + ((size_t)b * DD + d) * NN + n0 + nh;
#pragma unroll
    for (int k = 0; k < 4; ++k)
      *(half8*)(dst + k * 8) = *(const half8*)(tmp + k * 8);
  }
}

// ---------- flash attention: 2 q-tiles/wave, KVBLK=32, KV-split x3 (proven 93us) ----------
__global__ __launch_bounds__(256, 3) void k_flash(const f16* __restrict__ T, const f16* __restrict__ P,
                                                  const f16* __restrict__ Gdn, f16* __restrict__ accs,
                                                  float* __restrict__ ml) {
  __shared__ char smem[32768];
  int bid = blockIdx.x;
  int b = bid & 7;
  int u = bid >> 3;      // 0..95
  int hf = u % 3;        // split 0..2
  int qx = u / 3;        // 0..31
  int t0 = (hf == 2) ? 86 : hf * 43;  // first key-tile
  int nt = (hf == 2) ? 42 : 43;       // tiles in this split
  int tid = threadIdx.x;
  int lane = tid & 63, wave = tid >> 6;
  int lr = lane & 15, lg = lane >> 4;
  int q0 = qx * 128 + wave * 32;  // two tiles: q0..q0+15, q0+16..q0+31
  const f16* Tb = T + (size_t)b * NN * DD;
  const f16* Pb = P + ((size_t)b * NN + t0 * 32) * DD;
  const f16* Vb = Gdn + (size_t)b * DD * NN + t0 * 32;
  int srcq = 4 * lg;

  // hoisted staging bases
  const f16* kbase[2];
  const f16* vbase[2];
  char* kdst[2];
  char* vdst[2];
#pragma unroll
  for (int inst = 0; inst < 2; ++inst) {
    int t = inst * 256 + tid;
    int row = t >> 4, sp = t & 15, sl = sp ^ (row & 7);
    kbase[inst] = Pb + (size_t)PERM32(row) * DD + sl * 8;
    kdst[inst] = smem + (inst * 256 + wave * 64) * 16;
    int dv = t >> 2, gv = t & 3, glv = gv ^ ((dv >> 1) & 3);
    vbase[inst] = Vb + (size_t)dv * NN + glv * 8;
    vdst[inst] = smem + 16384 + (inst * 256 + wave * 64) * 16;
  }

  half8 qf[2][4];
  for (int qt = 0; qt < 2; ++qt)
    for (int ks = 0; ks < 4; ++ks) {
      half8 v = *(const half8*)(Tb + (size_t)(q0 + qt * 16 + lr) * DD + ks * 32 + lg * 8);
      for (int j = 0; j < 8; ++j) v[j] *= (f16)1.44269504f;  // log2(e) into Q
      qf[qt][ks] = v;
    }
  half8 ones;
  for (int j = 0; j < 8; ++j) ones[j] = (f16)1.f;

  f32x4 acc[2][8] = {};
  f32x4 lsum[2] = {};
  float m_run[2] = {-1e30f, -1e30f};

  // prologue: K(0), V(0)
#pragma unroll
  for (int inst = 0; inst < 2; ++inst) gload_lds16(kbase[inst], kdst[inst]);
#pragma unroll
  for (int inst = 0; inst < 2; ++inst) gload_lds16(vbase[inst], vdst[inst]);

  for (int kb = 0; kb < nt; ++kb) {
    int keyn = (kb < nt - 1) ? kb * 32 + 32 : 0;  // last prefetch harmless
    int cur = (kb & 1) * 8192, nxt = ((kb + 1) & 1) * 8192;
    char* Kc = smem + cur;
    char* Vc = smem + 16384 + cur;

    // issue K(kb+1)
    size_t ko = (size_t)keyn * DD;
#pragma unroll
    for (int inst = 0; inst < 2; ++inst) gload_lds16(kbase[inst] + ko, kdst[inst] + nxt);
    asm volatile("s_waitcnt vmcnt(4)" ::: "memory");  // K(kb) done; V(kb)+K(kb+1) in flight
    __builtin_amdgcn_sched_barrier(0);
    __builtin_amdgcn_s_barrier();  // B1
    __builtin_amdgcn_sched_barrier(0);

    // QK^T swapped, kf shared by both q-tiles
    f32x4 s[2][2];
    __builtin_amdgcn_s_setprio(1);
    for (int kt = 0; kt < 2; ++kt) {
      half8 kf[4];
      for (int ks = 0; ks < 4; ++ks)
        kf[ks] = *(const half8*)(Kc + (kt * 16 + lr) * 256 + (((ks * 4 + lg) ^ (lr & 7)) << 4));
      for (int qt = 0; qt < 2; ++qt) {
        f32x4 t = {};
        for (int ks = 0; ks < 4; ++ks) t = mfma16(kf[ks], qf[qt][ks], t);
        s[qt][kt] = t;
      }
    }
    __builtin_amdgcn_s_setprio(0);

    // two independent softmax chains (defer-max THR = 11.5 log2-units)
    half8 af[2];
    for (int qt = 0; qt < 2; ++qt) {
      float mx = fmaxf(fmaxf(s[qt][0][0], s[qt][0][1]), fmaxf(s[qt][0][2], s[qt][0][3]));
      mx = fmaxf(mx, fmaxf(fmaxf(s[qt][1][0], s[qt][1][1]), fmaxf(s[qt][1][2], s[qt][1][3])));
      mx = fmaxf(mx, __shfl_xor(mx, 16));
      mx = fmaxf(mx, __shfl_xor(mx, 32));
      bool grow = mx > m_run[qt] + 11.5f;
      if (__ballot(grow)) {
        float mn = fmaxf(m_run[qt], mx);
        float corr = EXP2(m_run[qt] - mn);
        m_run[qt] = mn;
        float c0 = __shfl(corr, srcq + 0), c1 = __shfl(corr, srcq + 1);
        float c2 = __shfl(corr, srcq + 2), c3 = __shfl(corr, srcq + 3);
        lsum[qt][0] *= c0; lsum[qt][1] *= c1; lsum[qt][2] *= c2; lsum[qt][3] *= c3;
        for (int nb = 0; nb < 8; ++nb) {
          acc[qt][nb][0] *= c0; acc[qt][nb][1] *= c1;
          acc[qt][nb][2] *= c2; acc[qt][nb][3] *= c3;
        }
      }
      for (int kt = 0; kt < 2; ++kt)
        for (int r = 0; r < 4; ++r)
          s[qt][kt][r] = EXP2(s[qt][kt][r] - m_run[qt]);
      union { half8 h8; half2t h2[4]; } un;
      un.h2[0] = pkrtz(s[qt][0][0], s[qt][0][1]);
      un.h2[1] = pkrtz(s[qt][0][2], s[qt][0][3]);
      un.h2[2] = pkrtz(s[qt][1][0], s[qt][1][1]);
      un.h2[3] = pkrtz(s[qt][1][2], s[qt][1][3]);
      af[qt] = un.h8;
      lsum[qt] = mfma16(af[qt], ones, lsum[qt]);
    }

    // issue V(kb+1)
#pragma unroll
    for (int inst = 0; inst < 2; ++inst) gload_lds16(vbase[inst] + keyn, vdst[inst] + nxt);
    asm volatile("s_waitcnt vmcnt(4)" ::: "memory");  // V(kb) done; K/V(kb+1) in flight
    __builtin_amdgcn_sched_barrier(0);
    __builtin_amdgcn_s_barrier();  // B2
    __builtin_amdgcn_sched_barrier(0);

    // PV: vf read once, both q-tiles consume
    __builtin_amdgcn_s_setprio(1);
    for (int nb = 0; nb < 8; ++nb) {
      int d = nb * 16 + lr;
      half8 vf = *(const half8*)(Vc + d * 64 + ((lg ^ ((d >> 1) & 3)) << 4));
      acc[0][nb] = mfma16(af[0], vf, acc[0][nb]);
      acc[1][nb] = mfma16(af[1], vf, acc[1][nb]);
    }
    __builtin_amdgcn_s_setprio(0);
  }
  asm volatile("s_waitcnt vmcnt(0)" ::: "memory");

  // epilogue: unnormalized acc + (m, l)
  size_t gq0 = (size_t)b * NN + q0;
  f16* A = accs + (size_t)hf * ((size_t)BB * NN * DD) + gq0 * DD;
  for (int qt = 0; qt < 2; ++qt)
    for (int nb = 0; nb < 8; ++nb)
      for (int r = 0; r < 4; ++r)
        A[(size_t)(qt * 16 + lg * 4 + r) * DD + nb * 16 + lr] = (f16)acc[qt][nb][r];
  float* mArr = ml + hf * 32768;
  float* lArr = ml + NSPLIT * 32768 + hf * 32768;
  if (lg == 0) {
    mArr[gq0 + lr] = m_run[0];
    mArr[gq0 + 16 + lr] = m_run[1];
  }
  if (lr == 0)
    for (int r = 0; r < 4; ++r) {
      lArr[gq0 + lg * 4 + r] = lsum[0][r];
      lArr[gq0 + 16 + lg * 4 + r] = lsum[1][r];
    }
}

// ---------- output projection + fused 3-way merge + BN stats ----------
// 256 blocks, each owns 128 rows (2 mt-tiles of 64), all 256 output channels.
__global__ __launch_bounds__(256) void k_gemm2(const f16* __restrict__ Y, const float* __restrict__ ml,
                                               const f16* __restrict__ Wwh, const float* __restrict__ wb,
                                               f16* __restrict__ wy, float* __restrict__ stats) {
  __shared__ float part[2][8][256];  // 16 KB
  const size_t SEG = (size_t)BB * NN * DD;
  int lane = threadIdx.x & 63, wave = threadIdx.x >> 6;
  int lr = lane & 15, lg = lane >> 4;
  int wr = wave >> 1, wc = wave & 1;
  float ps[4][2][2] = {};  // [yb][j][sum,sumsq]
  for (int mt = 0; mt < 2; ++mt) {
    int m0 = (blockIdx.x * 2 + mt) * 64 + wr * 32;
    // per-lane merge scales for rows m0+lr (i=0), m0+16+lr (i=1)
    f16 ch[2][NSPLIT];
    for (int i = 0; i < 2; ++i) {
      int row = m0 + i * 16 + lr;
      float m[NSPLIT], l[NSPLIT];
      float mm = -1e30f;
      for (int s = 0; s < NSPLIT; ++s) {
        m[s] = ml[s * 32768 + row];
        l[s] = ml[NSPLIT * 32768 + s * 32768 + row];
        mm = fmaxf(mm, m[s]);
      }
      float den = 0.f, c[NSPLIT];
      for (int s = 0; s < NSPLIT; ++s) {
        c[s] = EXP2(m[s] - mm);
        den += l[s] * c[s];
      }
      float inv = 1.f / den;
      for (int s = 0; s < NSPLIT; ++s) ch[i][s] = (f16)(c[s] * inv);
    }
    // merged A-fragments (read once per row)
    half8 a[2][4];
    for (int i = 0; i < 2; ++i)
      for (int k0 = 0; k0 < 4; ++k0) {
        size_t off = (size_t)(m0 + i * 16 + lr) * DD + k0 * 32 + lg * 8;
        half8 acc8 = *(const half8*)(Y + off) * ch[i][0];
        for (int s = 1; s < NSPLIT; ++s)
          acc8 = acc8 + *(const half8*)(Y + s * SEG + off) * ch[i][s];
        a[i][k0] = acc8;
      }
    for (int yb = 0; yb < 4; ++yb) {
      int c0 = yb * 64 + wc * 32;
      f32x4 acc[2][2] = {};
      for (int k0 = 0; k0 < 4; ++k0) {
        half8 w[2];
        for (int j = 0; j < 2; ++j)
          w[j] = *(const half8*)(Wwh + (size_t)(c0 + j * 16 + lr) * DD + k0 * 32 + lg * 8);
        for (int i = 0; i < 2; ++i)
          for (int j = 0; j < 2; ++j)
            acc[i][j] = mfma16(a[i][k0], w[j], acc[i][j]);
      }
      for (int i = 0; i < 2; ++i)
        for (int j = 0; j < 2; ++j) {
          float bias = wb[c0 + j * 16 + lr];
          for (int r = 0; r < 4; ++r) {
            int row = m0 + i * 16 + lg * 4 + r;
            int col = c0 + j * 16 + lr;
            float v = acc[i][j][r] + bias;
            wy[(size_t)row * CC + col] = (f16)v;
            ps[yb][j][0] += v;
            ps[yb][j][1] += v * v;
          }
        }
    }
  }
  for (int yb = 0; yb < 4; ++yb)
    for (int j = 0; j < 2; ++j) {
      int col = yb * 64 + wc * 32 + j * 16 + lr;
      part[0][wr * 4 + lg][col] = ps[yb][j][0];
      part[1][wr * 4 + lg][col] = ps[yb][j][1];
    }
  __syncthreads();
  {
    int col = threadIdx.x;
    for (int metric = 0; metric < 2; ++metric) {
      float s = 0.f;
      for (int wtr = 0; wtr < 8; ++wtr) s += part[metric][wtr][col];
      atomicAdd(&stats[metric * CC + col], s);
    }
  }
}

// ---------- BN apply + residual (vectorized transpose) ----------
// grid (NN/64, BB), 256 threads. Phase 1: wy [64n][256c] slab -> LDS [c][n] tile
// via 256B-contiguous half8 reads. Phase 2: per-c elementwise, 64B f32x4 segments.
__global__ __launch_bounds__(256) void k_bn_apply(const f16* __restrict__ wy, const float* __restrict__ x,
                                                  const float* __restrict__ stats, const float* __restrict__ gamma,
                                                  const float* __restrict__ beta, float* __restrict__ out) {
  __shared__ f16 tile[256][68];  // [c][n], pad 68 -> 8B-aligned b64 reads, 2-way banks
  int b = blockIdx.y, n0 = blockIdx.x * 64;
  int t = threadIdx.x;
  size_t base = (size_t)b * NN;
  // phase 1: 4 iters x (16 rows x 16 col-groups)
#pragma unroll
  for (int it = 0; it < 4; ++it) {
    int n = it * 16 + (t >> 4);
    int cg = t & 15;
    const f16* src = wy + (base + n0 + n) * CC;
    half8 v0 = *(const half8*)(src + cg * 8);
    half8 v1 = *(const half8*)(src + 128 + cg * 8);
#pragma unroll
    for (int k = 0; k < 8; ++k) {
      tile[cg * 8 + k][n] = v0[k];
      tile[128 + cg * 8 + k][n] = v1[k];
    }
  }
  __syncthreads();
  const float inv_cnt = 1.f / (float)(BB * NN);
  // phase 2: 4 c-groups; thread owns (c, 16-n quarter)
#pragma unroll
  for (int cc = 0; cc < 4; ++cc) {
    int c = cc * 64 + (t >> 2);
    int nq = (t & 3) * 16;
    float mean = stats[c] * inv_cnt;
    float var = stats[CC + c] * inv_cnt - mean * mean;
    float scale = gamma[c] * rsqrtf(var + BN_EPS);
    float bet = beta[c];
    size_t oi = ((size_t)b * CC + c) * NN + n0 + nq;
#pragma unroll
    for (int g = 0; g < 4; ++g) {
      half4 wv = *(const half4*)&tile[c][nq + g * 4];
      f32x4 xa = *(const f32x4*)(x + oi + g * 4);
      f32x4 o;
#pragma unroll
      for (int k = 0; k < 4; ++k)
        o[k] = ((float)wv[k] - mean) * scale + bet + xa[k];
      *(f32x4*)(out + oi + g * 4) = o;
    }
  }
}

extern "C" void kernel_launch(void* const* d_in, const int* in_sizes, int n_in,
                              void* d_out, int out_size, void* d_ws, size_t ws_size,
                              hipStream_t stream) {
  const float* x = (const float*)d_in[0];
  const float* tw = (const float*)d_in[1];
  const float* pw = (const float*)d_in[2];
  const float* gw = (const float*)d_in[3];
  const float* ww = (const float*)d_in[4];
  const float* wb = (const float*)d_in[5];
  const float* gamma = (const float*)d_in[6];
  const float* beta = (const float*)d_in[7];
  float* out = (float*)d_out;
  char* ws = (char*)d_ws;

  f16* Wcat = (f16*)(ws + 0);                 // 192 KB
  f16* Wwh = (f16*)(ws + 196608);             // 64 KB
  float* stats = (float*)(ws + 262144);       // 2 KB
  float* ml = (float*)(ws + 524288);          // 768 KB: m[3][32768], l[3][32768]
  const size_t BASE = 1 << 21;                // 2 MB
  f16* T = (f16*)(ws + BASE);                 // 8 MB
  f16* P = (f16*)(ws + BASE + 8388608);       // 8 MB
  f16* Gdn = (f16*)(ws + BASE + 16777216);    // 8 MB
  f16* accs = (f16*)(ws + BASE + 25165824);   // 3 x 8 MB unnormalized splits
  f16* wy = (f16*)(ws + BASE);                // 16 MB (reuses dead T+P region)

  k_cast_weights<<<512, 256, 0, stream>>>(tw, pw, gw, ww, Wcat, Wwh, stats);
  k_gemm1<<<dim3(NN / 64, BB), 256, 0, stream>>>(x, Wcat, T, P, Gdn);
  k_flash<<<768, 256, 0, stream>>>(T, P, Gdn, accs, ml);
  k_gemm2<<<256, 256, 0, stream>>>(accs, ml, Wwh, wb, wy, stats);
  k_bn_apply<<<dim3(NN / 64, BB), 256, 0, stream>>>(wy, x, stats, gamma, beta, out);
}

// Round 19
// 158.015 us; speedup vs baseline: 1.0967x; 1.0207x over previous
//
#include <hip/hip_runtime.h>

#define BB 8
#define CC 256
#define DD 128
#define NN 4096
#define BN_EPS 1e-5f
#define NSPLIT 3

typedef _Float16 f16;
typedef _Float16 half8 __attribute__((ext_vector_type(8)));
typedef _Float16 half2t __attribute__((ext_vector_type(2)));
typedef float f32x4 __attribute__((ext_vector_type(4)));

__device__ __forceinline__ f32x4 mfma16(half8 a, half8 b, f32x4 c) {
  return __builtin_amdgcn_mfma_f32_16x16x32_f16(a, b, c, 0, 0, 0);
}

__device__ __forceinline__ void gload_lds16(const void* g, void* l) {
  __builtin_amdgcn_global_load_lds((const __attribute__((address_space(1))) void*)g,
                                   (__attribute__((address_space(3))) void*)l, 16, 0, 0);
}

__device__ __forceinline__ half2t pkrtz(float a, float b) {
  auto t = __builtin_amdgcn_cvt_pkrtz(a, b);
  return __builtin_bit_cast(half2t, t);
}

#define EXP2(x) __builtin_amdgcn_exp2f(x)

// key permutation for 32-key tiles: swapped-QK register layout feeds PV A-frag directly.
#define PERM32(i) ((((i) >> 2) & 3) * 8 + (((i) >> 4) & 1) * 4 + ((i) & 3))

// ---------- weights cast (fp32 -> fp16), stats zero ----------
__global__ void k_cast_weights(const float* __restrict__ tw, const float* __restrict__ pw,
                               const float* __restrict__ gw, const float* __restrict__ ww,
                               f16* __restrict__ Wcat, f16* __restrict__ Wwh,
                               float* __restrict__ stats) {
  int i = blockIdx.x * 256 + threadIdx.x;
  if (i < 32768) Wcat[i] = (f16)tw[i];
  else if (i < 65536) Wcat[i] = (f16)pw[i - 32768];
  else if (i < 98304) Wcat[i] = (f16)gw[i - 65536];
  else if (i < 131072) Wwh[i - 98304] = (f16)ww[i - 98304];
  if (i < 512) stats[i] = 0.f;
}

// ---------- fused projections: x staged+transposed in LDS, G transposed in LDS ----------
__global__ __launch_bounds__(256) void k_gemm1(const float* __restrict__ x, const f16* __restrict__ Wcat,
                                               f16* __restrict__ T, f16* __restrict__ P,
                                               f16* __restrict__ Gdn) {
  __shared__ char xls[32768];  // xl[n 64][c 256] f16, granule-swizzled
  __shared__ char gls[16384];  // gl[n 64][d 128] f16, granule-swizzled
  int b = blockIdx.y;
  int n0 = blockIdx.x * 64;
  int tid = threadIdx.x;
  int lane = tid & 63, wave = tid >> 6;
  int lr = lane & 15, lg = lane >> 4;
  int wr = wave >> 1, wc = wave & 1;

  {
    int c = tid;
    const float* src = x + ((size_t)b * CC + c) * NN + n0;
#pragma unroll
    for (int n4 = 0; n4 < 64; n4 += 4) {
      f32x4 v = *(const f32x4*)(src + n4);
#pragma unroll
      for (int k = 0; k < 4; ++k) {
        int n = n4 + k;
        *(f16*)(xls + n * 512 + ((((c >> 3) ^ (n & 7)) * 8 + (c & 7)) * 2)) = (f16)v[k];
      }
    }
  }
  __syncthreads();

  half8 a[2][8];
#pragma unroll
  for (int i = 0; i < 2; ++i) {
    int nloc = wr * 32 + i * 16 + lr;
#pragma unroll
    for (int k0 = 0; k0 < 8; ++k0)
      a[i][k0] = *(const half8*)(xls + nloc * 512 + (((k0 * 4 + lg) ^ (nloc & 7)) << 4));
  }

  size_t base = (size_t)b * NN + n0;
#pragma unroll
  for (int yb = 0; yb < 6; ++yb) {
    int c0 = yb * 64 + wc * 32;
    f32x4 acc[2][2] = {};
#pragma unroll
    for (int k0 = 0; k0 < 8; ++k0) {
      half8 w[2];
      for (int j = 0; j < 2; ++j)
        w[j] = *(const half8*)(Wcat + (size_t)(c0 + j * 16 + lr) * CC + k0 * 32 + lg * 8);
      for (int i = 0; i < 2; ++i)
        for (int j = 0; j < 2; ++j)
          acc[i][j] = mfma16(a[i][k0], w[j], acc[i][j]);
    }
    if (yb < 4) {
      f16* dst = (yb < 2) ? T : P;
      int cl0 = (yb & 1) * 64 + wc * 32;
      for (int i = 0; i < 2; ++i)
        for (int j = 0; j < 2; ++j)
          for (int r = 0; r < 4; ++r) {
            int row = wr * 32 + i * 16 + lg * 4 + r;
            int col = cl0 + j * 16 + lr;
            dst[(base + row) * DD + col] = (f16)acc[i][j][r];
          }
    } else {
      for (int i = 0; i < 2; ++i)
        for (int j = 0; j < 2; ++j)
          for (int r = 0; r < 4; ++r) {
            int n = wr * 32 + i * 16 + lg * 4 + r;
            int d = (yb - 4) * 64 + wc * 32 + j * 16 + lr;
            *(f16*)(gls + n * 256 + ((((d >> 3) ^ (n & 7)) * 8 + (d & 7)) * 2)) = (f16)acc[i][j][r];
          }
    }
  }
  __syncthreads();
  {
    int d = tid >> 1, nh = (tid & 1) * 32;
    f16 tmp[32];
#pragma unroll
    for (int k = 0; k < 32; ++k) {
      int n = nh + k;
      tmp[k] = *(const f16*)(gls + n * 256 + ((((d >> 3) ^ (n & 7)) * 8 + (d & 7)) * 2));
    }
    f16* dst = Gdn + ((size_t)b * DD + d) * NN + n0 + nh;
#pragma unroll
    for (int k = 0; k < 4; ++k)
      *(half8*)(dst + k * 8) = *(const half8*)(tmp + k * 8);
  }
}

// ---------- flash attention: 2 q-tiles/wave, KVBLK=32, KV-split x3 (proven 93us) ----------
__global__ __launch_bounds__(256, 3) void k_flash(const f16* __restrict__ T, const f16* __restrict__ P,
                                                  const f16* __restrict__ Gdn, f16* __restrict__ accs,
                                                  float* __restrict__ ml) {
  __shared__ char smem[32768];
  int bid = blockIdx.x;
  int b = bid & 7;
  int u = bid >> 3;      // 0..95
  int hf = u % 3;        // split 0..2
  int qx = u / 3;        // 0..31
  int t0 = (hf == 2) ? 86 : hf * 43;  // first key-tile
  int nt = (hf == 2) ? 42 : 43;       // tiles in this split
  int tid = threadIdx.x;
  int lane = tid & 63, wave = tid >> 6;
  int lr = lane & 15, lg = lane >> 4;
  int q0 = qx * 128 + wave * 32;  // two tiles: q0..q0+15, q0+16..q0+31
  const f16* Tb = T + (size_t)b * NN * DD;
  const f16* Pb = P + ((size_t)b * NN + t0 * 32) * DD;
  const f16* Vb = Gdn + (size_t)b * DD * NN + t0 * 32;
  int srcq = 4 * lg;

  // hoisted staging bases
  const f16* kbase[2];
  const f16* vbase[2];
  char* kdst[2];
  char* vdst[2];
#pragma unroll
  for (int inst = 0; inst < 2; ++inst) {
    int t = inst * 256 + tid;
    int row = t >> 4, sp = t & 15, sl = sp ^ (row & 7);
    kbase[inst] = Pb + (size_t)PERM32(row) * DD + sl * 8;
    kdst[inst] = smem + (inst * 256 + wave * 64) * 16;
    int dv = t >> 2, gv = t & 3, glv = gv ^ ((dv >> 1) & 3);
    vbase[inst] = Vb + (size_t)dv * NN + glv * 8;
    vdst[inst] = smem + 16384 + (inst * 256 + wave * 64) * 16;
  }

  half8 qf[2][4];
  for (int qt = 0; qt < 2; ++qt)
    for (int ks = 0; ks < 4; ++ks) {
      half8 v = *(const half8*)(Tb + (size_t)(q0 + qt * 16 + lr) * DD + ks * 32 + lg * 8);
      for (int j = 0; j < 8; ++j) v[j] *= (f16)1.44269504f;  // log2(e) into Q
      qf[qt][ks] = v;
    }
  half8 ones;
  for (int j = 0; j < 8; ++j) ones[j] = (f16)1.f;

  f32x4 acc[2][8] = {};
  f32x4 lsum[2] = {};
  float m_run[2] = {-1e30f, -1e30f};

  // prologue: K(0), V(0)
#pragma unroll
  for (int inst = 0; inst < 2; ++inst) gload_lds16(kbase[inst], kdst[inst]);
#pragma unroll
  for (int inst = 0; inst < 2; ++inst) gload_lds16(vbase[inst], vdst[inst]);

  for (int kb = 0; kb < nt; ++kb) {
    int keyn = (kb < nt - 1) ? kb * 32 + 32 : 0;  // last prefetch harmless
    int cur = (kb & 1) * 8192, nxt = ((kb + 1) & 1) * 8192;
    char* Kc = smem + cur;
    char* Vc = smem + 16384 + cur;

    // issue K(kb+1)
    size_t ko = (size_t)keyn * DD;
#pragma unroll
    for (int inst = 0; inst < 2; ++inst) gload_lds16(kbase[inst] + ko, kdst[inst] + nxt);
    asm volatile("s_waitcnt vmcnt(4)" ::: "memory");  // K(kb) done; V(kb)+K(kb+1) in flight
    __builtin_amdgcn_sched_barrier(0);
    __builtin_amdgcn_s_barrier();  // B1
    __builtin_amdgcn_sched_barrier(0);

    // QK^T swapped, kf shared by both q-tiles
    f32x4 s[2][2];
    __builtin_amdgcn_s_setprio(1);
    for (int kt = 0; kt < 2; ++kt) {
      half8 kf[4];
      for (int ks = 0; ks < 4; ++ks)
        kf[ks] = *(const half8*)(Kc + (kt * 16 + lr) * 256 + (((ks * 4 + lg) ^ (lr & 7)) << 4));
      for (int qt = 0; qt < 2; ++qt) {
        f32x4 t = {};
        for (int ks = 0; ks < 4; ++ks) t = mfma16(kf[ks], qf[qt][ks], t);
        s[qt][kt] = t;
      }
    }
    __builtin_amdgcn_s_setprio(0);

    // two independent softmax chains (defer-max THR = 11.5 log2-units)
    half8 af[2];
    for (int qt = 0; qt < 2; ++qt) {
      float mx = fmaxf(fmaxf(s[qt][0][0], s[qt][0][1]), fmaxf(s[qt][0][2], s[qt][0][3]));
      mx = fmaxf(mx, fmaxf(fmaxf(s[qt][1][0], s[qt][1][1]), fmaxf(s[qt][1][2], s[qt][1][3])));
      mx = fmaxf(mx, __shfl_xor(mx, 16));
      mx = fmaxf(mx, __shfl_xor(mx, 32));
      bool grow = mx > m_run[qt] + 11.5f;
      if (__ballot(grow)) {
        float mn = fmaxf(m_run[qt], mx);
        float corr = EXP2(m_run[qt] - mn);
        m_run[qt] = mn;
        float c0 = __shfl(corr, srcq + 0), c1 = __shfl(corr, srcq + 1);
        float c2 = __shfl(corr, srcq + 2), c3 = __shfl(corr, srcq + 3);
        lsum[qt][0] *= c0; lsum[qt][1] *= c1; lsum[qt][2] *= c2; lsum[qt][3] *= c3;
        for (int nb = 0; nb < 8; ++nb) {
          acc[qt][nb][0] *= c0; acc[qt][nb][1] *= c1;
          acc[qt][nb][2] *= c2; acc[qt][nb][3] *= c3;
        }
      }
      for (int kt = 0; kt < 2; ++kt)
        for (int r = 0; r < 4; ++r)
          s[qt][kt][r] = EXP2(s[qt][kt][r] - m_run[qt]);
      union { half8 h8; half2t h2[4]; } un;
      un.h2[0] = pkrtz(s[qt][0][0], s[qt][0][1]);
      un.h2[1] = pkrtz(s[qt][0][2], s[qt][0][3]);
      un.h2[2] = pkrtz(s[qt][1][0], s[qt][1][1]);
      un.h2[3] = pkrtz(s[qt][1][2], s[qt][1][3]);
      af[qt] = un.h8;
      lsum[qt] = mfma16(af[qt], ones, lsum[qt]);
    }

    // issue V(kb+1)
#pragma unroll
    for (int inst = 0; inst < 2; ++inst) gload_lds16(vbase[inst] + keyn, vdst[inst] + nxt);
    asm volatile("s_waitcnt vmcnt(4)" ::: "memory");  // V(kb) done; K/V(kb+1) in flight
    __builtin_amdgcn_sched_barrier(0);
    __builtin_amdgcn_s_barrier();  // B2
    __builtin_amdgcn_sched_barrier(0);

    // PV: vf read once, both q-tiles consume
    __builtin_amdgcn_s_setprio(1);
    for (int nb = 0; nb < 8; ++nb) {
      int d = nb * 16 + lr;
      half8 vf = *(const half8*)(Vc + d * 64 + ((lg ^ ((d >> 1) & 3)) << 4));
      acc[0][nb] = mfma16(af[0], vf, acc[0][nb]);
      acc[1][nb] = mfma16(af[1], vf, acc[1][nb]);
    }
    __builtin_amdgcn_s_setprio(0);
  }
  asm volatile("s_waitcnt vmcnt(0)" ::: "memory");

  // epilogue: unnormalized acc + (m, l)
  size_t gq0 = (size_t)b * NN + q0;
  f16* A = accs + (size_t)hf * ((size_t)BB * NN * DD) + gq0 * DD;
  for (int qt = 0; qt < 2; ++qt)
    for (int nb = 0; nb < 8; ++nb)
      for (int r = 0; r < 4; ++r)
        A[(size_t)(qt * 16 + lg * 4 + r) * DD + nb * 16 + lr] = (f16)acc[qt][nb][r];
  float* mArr = ml + hf * 32768;
  float* lArr = ml + NSPLIT * 32768 + hf * 32768;
  if (lg == 0) {
    mArr[gq0 + lr] = m_run[0];
    mArr[gq0 + 16 + lr] = m_run[1];
  }
  if (lr == 0)
    for (int r = 0; r < 4; ++r) {
      lArr[gq0 + lg * 4 + r] = lsum[0][r];
      lArr[gq0 + 16 + lg * 4 + r] = lsum[1][r];
    }
}

// ---------- output projection + fused 3-way merge + BN stats ----------
// 256 blocks, each owns 128 rows (2 mt-tiles of 64), all 256 output channels.
__global__ __launch_bounds__(256) void k_gemm2(const f16* __restrict__ Y, const float* __restrict__ ml,
                                               const f16* __restrict__ Wwh, const float* __restrict__ wb,
                                               f16* __restrict__ wy, float* __restrict__ stats) {
  __shared__ float part[2][8][256];  // 16 KB
  const size_t SEG = (size_t)BB * NN * DD;
  int lane = threadIdx.x & 63, wave = threadIdx.x >> 6;
  int lr = lane & 15, lg = lane >> 4;
  int wr = wave >> 1, wc = wave & 1;
  float ps[4][2][2] = {};  // [yb][j][sum,sumsq]
  for (int mt = 0; mt < 2; ++mt) {
    int m0 = (blockIdx.x * 2 + mt) * 64 + wr * 32;
    // per-lane merge scales for rows m0+lr (i=0), m0+16+lr (i=1)
    f16 ch[2][NSPLIT];
    for (int i = 0; i < 2; ++i) {
      int row = m0 + i * 16 + lr;
      float m[NSPLIT], l[NSPLIT];
      float mm = -1e30f;
      for (int s = 0; s < NSPLIT; ++s) {
        m[s] = ml[s * 32768 + row];
        l[s] = ml[NSPLIT * 32768 + s * 32768 + row];
        mm = fmaxf(mm, m[s]);
      }
      float den = 0.f, c[NSPLIT];
      for (int s = 0; s < NSPLIT; ++s) {
        c[s] = EXP2(m[s] - mm);
        den += l[s] * c[s];
      }
      float inv = 1.f / den;
      for (int s = 0; s < NSPLIT; ++s) ch[i][s] = (f16)(c[s] * inv);
    }
    // merged A-fragments (read once per row)
    half8 a[2][4];
    for (int i = 0; i < 2; ++i)
      for (int k0 = 0; k0 < 4; ++k0) {
        size_t off = (size_t)(m0 + i * 16 + lr) * DD + k0 * 32 + lg * 8;
        half8 acc8 = *(const half8*)(Y + off) * ch[i][0];
        for (int s = 1; s < NSPLIT; ++s)
          acc8 = acc8 + *(const half8*)(Y + s * SEG + off) * ch[i][s];
        a[i][k0] = acc8;
      }
    for (int yb = 0; yb < 4; ++yb) {
      int c0 = yb * 64 + wc * 32;
      f32x4 acc[2][2] = {};
      for (int k0 = 0; k0 < 4; ++k0) {
        half8 w[2];
        for (int j = 0; j < 2; ++j)
          w[j] = *(const half8*)(Wwh + (size_t)(c0 + j * 16 + lr) * DD + k0 * 32 + lg * 8);
        for (int i = 0; i < 2; ++i)
          for (int j = 0; j < 2; ++j)
            acc[i][j] = mfma16(a[i][k0], w[j], acc[i][j]);
      }
      for (int i = 0; i < 2; ++i)
        for (int j = 0; j < 2; ++j) {
          float bias = wb[c0 + j * 16 + lr];
          for (int r = 0; r < 4; ++r) {
            int row = m0 + i * 16 + lg * 4 + r;
            int col = c0 + j * 16 + lr;
            float v = acc[i][j][r] + bias;
            wy[(size_t)row * CC + col] = (f16)v;
            ps[yb][j][0] += v;
            ps[yb][j][1] += v * v;
          }
        }
    }
  }
  for (int yb = 0; yb < 4; ++yb)
    for (int j = 0; j < 2; ++j) {
      int col = yb * 64 + wc * 32 + j * 16 + lr;
      part[0][wr * 4 + lg][col] = ps[yb][j][0];
      part[1][wr * 4 + lg][col] = ps[yb][j][1];
    }
  __syncthreads();
  {
    int col = threadIdx.x;
    for (int metric = 0; metric < 2; ++metric) {
      float s = 0.f;
      for (int wtr = 0; wtr < 8; ++wtr) s += part[metric][wtr][col];
      atomicAdd(&stats[metric * CC + col], s);
    }
  }
}

// ---------- BN apply + residual (R15-proven high-parallelism transpose) ----------
__global__ void k_bn_apply(const f16* __restrict__ wy, const float* __restrict__ x,
                           const float* __restrict__ stats, const float* __restrict__ gamma,
                           const float* __restrict__ beta, float* __restrict__ out) {
  __shared__ f16 tile[32][33];
  int b = blockIdx.z, c0 = blockIdx.y * 32, n0 = blockIdx.x * 32;
  int tx = threadIdx.x, ty = threadIdx.y;
  for (int j = 0; j < 4; ++j) {
    int nn = ty + j * 8;
    tile[nn][tx] = wy[((size_t)b * NN + n0 + nn) * CC + c0 + tx];
  }
  __syncthreads();
  const float inv_cnt = 1.f / (float)(BB * NN);
  for (int j = 0; j < 4; ++j) {
    int cc = ty + j * 8;
    int c = c0 + cc;
    float mean = stats[c] * inv_cnt;
    float var = stats[CC + c] * inv_cnt - mean * mean;
    float scale = gamma[c] * rsqrtf(var + BN_EPS);
    size_t oi = ((size_t)b * CC + c) * NN + n0 + tx;
    out[oi] = ((float)tile[tx][cc] - mean) * scale + beta[c] + x[oi];
  }
}

extern "C" void kernel_launch(void* const* d_in, const int* in_sizes, int n_in,
                              void* d_out, int out_size, void* d_ws, size_t ws_size,
                              hipStream_t stream) {
  const float* x = (const float*)d_in[0];
  const float* tw = (const float*)d_in[1];
  const float* pw = (const float*)d_in[2];
  const float* gw = (const float*)d_in[3];
  const float* ww = (const float*)d_in[4];
  const float* wb = (const float*)d_in[5];
  const float* gamma = (const float*)d_in[6];
  const float* beta = (const float*)d_in[7];
  float* out = (float*)d_out;
  char* ws = (char*)d_ws;

  f16* Wcat = (f16*)(ws + 0);                 // 192 KB
  f16* Wwh = (f16*)(ws + 196608);             // 64 KB
  float* stats = (float*)(ws + 262144);       // 2 KB
  float* ml = (float*)(ws + 524288);          // 768 KB: m[3][32768], l[3][32768]
  const size_t BASE = 1 << 21;                // 2 MB
  f16* T = (f16*)(ws + BASE);                 // 8 MB
  f16* P = (f16*)(ws + BASE + 8388608);       // 8 MB
  f16* Gdn = (f16*)(ws + BASE + 16777216);    // 8 MB
  f16* accs = (f16*)(ws + BASE + 25165824);   // 3 x 8 MB unnormalized splits
  f16* wy = (f16*)(ws + BASE);                // 16 MB (reuses dead T+P region)

  k_cast_weights<<<512, 256, 0, stream>>>(tw, pw, gw, ww, Wcat, Wwh, stats);
  k_gemm1<<<dim3(NN / 64, BB), 256, 0, stream>>>(x, Wcat, T, P, Gdn);
  k_flash<<<768, 256, 0, stream>>>(T, P, Gdn, accs, ml);
  k_gemm2<<<256, 256, 0, stream>>>(accs, ml, Wwh, wb, wy, stats);
  k_bn_apply<<<dim3(NN / 32, CC / 32, BB), dim3(32, 8), 0, stream>>>(wy, x, stats, gamma, beta, out);
}